// Round 18
// baseline (244.332 us; speedup 1.0000x reference)
//
#include <hip/hip_runtime.h>
#include <hip/hip_bf16.h>

#define BATCH 32
#define T 1024
#define G 2                       // pipeline stages (blocks) per batch
#define WVS 4                     // 4 waves = 1 wave/SIMD, all 4 SIMDs
#define CPT 2                     // columns per thread
#define NTH 256                   // 256 threads × 2 cols = 512 cols per stage
#define KS 16                     // steps per barrier window = rows per chunk
#define DOW 91                    // >=63+KS (ring proof, lag 28) and 3*DOW+63 ≡ 0 mod 16
#define SKEW (DOW * (WVS - 1) + 63)   // 336 (16-aligned)
#define TOT (SKEW + T)            // 1360 = NB*KS exactly (no overhang)
#define NB (TOT / KS)             // 85 windows
#define NCHUNK (T / KS)           // 64 chunks per interface
#define MARGIN 4                  // startup lead (chunks)
#define SENT_U 0xAAAAAAAAu
#define BIGF 1e10f
#define K2f 14.426950408889634f   // 1/(gamma*ln2), gamma=0.1
#define GLN2f 0.0693147180559945f // gamma*ln2
#define KQTSE_ 0.1f

// workspace layout
#define EDGE_BYTES (BATCH * T * 4)  // 131072: one interface per batch (G=2)
#define SDTW_OFF EDGE_BYTES
#define WS_NEEDED (size_t)(SDTW_OFF + BATCH * 4)

typedef float f32x4 __attribute__((ext_vector_type(4)));

// Raw v_exp_f32 (R14-proven: exp2f's __ocml fixup cost ~40% of the cell).
__device__ __forceinline__ float fexp2(float x) {
    float r;
    asm("v_exp_f32 %0, %1" : "=v"(r) : "v"(x));
    return r;
}

// Exact softmin_gamma(a,b,c): m - g*ln(1 + 2^{K(m-md)} + 2^{K(m-M)}) (one exp folded).
__device__ __forceinline__ float softmin3(float a, float b, float c) {
    float m  = fminf(fminf(a, b), c);             // v_min3_f32
    float M  = fmaxf(fmaxf(a, b), c);             // v_max3_f32
    float md = __builtin_amdgcn_fmed3f(a, b, c);  // v_med3_f32
    float mk = m * K2f;
    float e1 = fexp2(fmaf(-K2f, md, mk));
    float e2 = fexp2(fmaf(-K2f, M, mk));
    return fmaf(-GLN2f, __log2f(1.0f + e1 + e2), m);
}

// lane i gets src[lane i-1]; lane 0 keeps `old` (bound_ctrl=false fuses the select).
__device__ __forceinline__ float lane_shr1(float old, float src) {
    return __int_as_float(__builtin_amdgcn_update_dpp(
        __float_as_int(old), __float_as_int(src), 0x138, 0xF, 0xF, false));
}

// Raw barrier draining ONLY lgkmcnt (R15-proven): producer's global stores and
// consumer's in-flight loads stay pending across it.
__device__ __forceinline__ void block_sync_lds() {
    __builtin_amdgcn_sched_barrier(0);
    asm volatile("s_waitcnt lgkmcnt(0)" ::: "memory");
    __builtin_amdgcn_s_barrier();
    __builtin_amdgcn_sched_barrier(0);
}

// ---- device-coherent transport (R13/R15-proven), 16-row (64B) chunks ----
__device__ __forceinline__ void issue_load16(const float* base, f32x4& a, f32x4& b,
                                             f32x4& c, f32x4& d) {
    asm volatile("global_load_dwordx4 %0, %4, off sc0 sc1\n\t"
                 "global_load_dwordx4 %1, %4, off offset:16 sc0 sc1\n\t"
                 "global_load_dwordx4 %2, %4, off offset:32 sc0 sc1\n\t"
                 "global_load_dwordx4 %3, %4, off offset:48 sc0 sc1"
                 : "=&v"(a), "=&v"(b), "=&v"(c), "=&v"(d) : "v"(base));
}
__device__ __forceinline__ void await_load16(f32x4& a, f32x4& b, f32x4& c, f32x4& d) {
    asm volatile("s_waitcnt vmcnt(0)" : "+v"(a), "+v"(b), "+v"(c), "+v"(d) :: "memory");
    __builtin_amdgcn_sched_barrier(0);
}
__device__ __forceinline__ bool sent1(const f32x4& a) {
    return (__float_as_uint(a.x) == SENT_U) | (__float_as_uint(a.y) == SENT_U) |
           (__float_as_uint(a.z) == SENT_U) | (__float_as_uint(a.w) == SENT_U);
}
__device__ __forceinline__ bool has_sent16(const f32x4& a, const f32x4& b,
                                           const f32x4& c, const f32x4& d) {
    return sent1(a) | sent1(b) | sent1(c) | sent1(d);
}
__device__ __forceinline__ void spin_load16(const float* base, f32x4& a, f32x4& b,
                                            f32x4& c, f32x4& d) {
    issue_load16(base, a, b, c, d);
    await_load16(a, b, c, d);
    while (has_sent16(a, b, c, d)) {
        __builtin_amdgcn_s_sleep(8);
        issue_load16(base, a, b, c, d);
        await_load16(a, b, c, d);
    }
}
__device__ __forceinline__ void store_edge16(float* base, const f32x4& a, const f32x4& b,
                                             const f32x4& c, const f32x4& d) {
    asm volatile("global_store_dwordx4 %0, %1, off sc0 sc1\n\t"
                 "global_store_dwordx4 %0, %2, off offset:16 sc0 sc1\n\t"
                 "global_store_dwordx4 %0, %3, off offset:32 sc0 sc1\n\t"
                 "global_store_dwordx4 %0, %4, off offset:48 sc0 sc1"
                 :: "v"(base), "v"(a), "v"(b), "v"(c), "v"(d) : "memory");
}

// G=2 pipelined skewed-wave systolic soft-DTW, W4/C2/KS16.
// Block (b,g) owns cols [g*512,(g+1)*512), 2 cols/thread, 4 waves (1/SIMD).
// Per-step chain = 2 serial softmins (~issue-matched; the R17 lesson was that
// C=4's 4-softmin chain exceeded issue). Intra-block: DPP left edge + LDS ring
// + raw lgkmcnt-barrier per KS=16 steps (lag DOW-63=28>=KS keeps the proof).
// Inter-block: stage 0's col-511 streams to stage 1 in 16-aligned 64B chunks
// (sentinel-validated, issue-before-compute / await-after). Garbage-cell
// reachability arguments identical to R16/R17-proven kernels.
__global__ __launch_bounds__(NTH) void sdtw_pipe(const float* __restrict__ pred,
                                                 const float* __restrict__ targ,
                                                 float* __restrict__ edges,
                                                 float* __restrict__ sdtw_out) {
    __shared__ float p[T];
    __shared__ float ring[WVS - 1][T];   // 12 KB

    const int blk = blockIdx.x;
    const int b = blk & (BATCH - 1);
    const int g = blk >> 5;
    const int tid = threadIdx.x;
    const int wv = tid >> 6;
    const int ln = tid & 63;
    const int myoff = DOW * wv + ln;

    ((float4*)p)[tid] = ((const float4*)(pred + b * T))[tid];
    const float2 t2 = ((const float2*)(targ + b * T + g * (T / G)))[tid];
    const float tj0 = t2.x, tj1 = t2.y;
    const float zcc = (g == 0 && tid == 0) ? 0.0f : BIGF;   // R[0][0]=0 else BIG

    float* eb = edges + b * T;           // single interface per batch (G=2)
    const bool consumer = (g == 1) && (tid == 0);
    const bool producing = (g == 0) && (tid == NTH - 1);   // wv3 ln63, col 511

    float top0 = BIGF, top1 = BIGF, corner = BIGF, rc = BIGF, result = 0.0f;
    float rlg[KS];
#pragma unroll
    for (int i = 0; i < KS; ++i) rlg[i] = BIGF;

    __syncthreads();   // full barrier once (stage loads + p LDS)

    if (consumer) {
        f32x4 a, b4, c4, d4;
        spin_load16(eb + (MARGIN - 1) * KS, a, b4, c4, d4);  // startup lead
        spin_load16(eb, a, b4, c4, d4);                      // chunk 0
        rlg[0]=a.x; rlg[1]=a.y; rlg[2]=a.z; rlg[3]=a.w;
        rlg[4]=b4.x; rlg[5]=b4.y; rlg[6]=b4.z; rlg[7]=b4.w;
        rlg[8]=c4.x; rlg[9]=c4.y; rlg[10]=c4.z; rlg[11]=c4.w;
        rlg[12]=d4.x; rlg[13]=d4.y; rlg[14]=d4.z; rlg[15]=d4.w;
    }

    for (int sb = 0; sb < NB; ++sb) {
        const int ics = sb * KS - myoff;

        // lane-0 left-edge batch (off the dependence chain)
        float rl[KS];
#pragma unroll
        for (int so = 0; so < KS; ++so) rl[so] = BIGF;
        if (ln == 0) {
            if (wv > 0) {
#pragma unroll
                for (int so = 0; so < KS; ++so) rl[so] = ring[wv - 1][(ics + so) & (T - 1)];
            } else if (g == 1) {
#pragma unroll
                for (int so = 0; so < KS; ++so) rl[so] = rlg[so];
            }
        }

        // squared distances for this window (off the dependence chain)
        float Dv0[KS], Dv1[KS];
#pragma unroll
        for (int so = 0; so < KS; ++so) {
            const float pr = p[(ics + so) & (T - 1)];
            const float d0 = pr - tj0, d1 = pr - tj1;
            Dv0[so] = d0 * d0; Dv1[so] = d1 * d1;
        }

        // consumer: issue next chunk's loads now, validate after compute
        f32x4 na, nb4, nc4, nd4;
        const bool want = consumer && (sb + 1) < NCHUNK;
        const float* basep = eb + (sb + 1) * KS;
        if (want) issue_load16(basep, na, nb4, nc4, nd4);

        float erow[KS];
#pragma unroll
        for (int so = 0; so < KS; ++so) {
            const int ic = ics + so;
            const float lf = lane_shr1(rl[so], rc);   // left edge (lane0 keeps rl)
            const bool r0 = (ic == 0);
            const float t0 = r0 ? BIGF : top0;
            const float t1 = r0 ? BIGF : top1;
            const float cc = r0 ? zcc : corner;

            const float c0 = Dv0[so] + softmin3(cc, t0, lf);
            const float c1 = Dv1[so] + softmin3(t0, t1, c0);

            rc = c1; top0 = c0; top1 = c1; corner = lf; result = c1;
            erow[so] = c1;
            if (ln == 63 && wv < WVS - 1 && (unsigned)ic < (unsigned)T)
                ring[wv][ic] = c1;
        }

        // producer: publish completed 16-aligned chunk (fire-and-forget;
        // sentinel validation orders it, barrier does NOT drain vmcnt)
        if (producing && ics >= 0) {
            f32x4 ea = {erow[0], erow[1], erow[2], erow[3]};
            f32x4 eb2 = {erow[4], erow[5], erow[6], erow[7]};
            f32x4 ec = {erow[8], erow[9], erow[10], erow[11]};
            f32x4 ed = {erow[12], erow[13], erow[14], erow[15]};
            store_edge16(eb + ics, ea, eb2, ec, ed);
        }

        if (want) {
            await_load16(na, nb4, nc4, nd4);
            while (has_sent16(na, nb4, nc4, nd4)) {   // rare: lead absorbed jitter
                __builtin_amdgcn_s_sleep(2);
                issue_load16(basep, na, nb4, nc4, nd4);
                await_load16(na, nb4, nc4, nd4);
            }
            rlg[0]=na.x; rlg[1]=na.y; rlg[2]=na.z; rlg[3]=na.w;
            rlg[4]=nb4.x; rlg[5]=nb4.y; rlg[6]=nb4.z; rlg[7]=nb4.w;
            rlg[8]=nc4.x; rlg[9]=nc4.y; rlg[10]=nc4.z; rlg[11]=nc4.w;
            rlg[12]=nd4.x; rlg[13]=nd4.y; rlg[14]=nd4.z; rlg[15]=nd4.w;
        }
        block_sync_lds();   // lgkmcnt-only drain: ring ordered, vmem flies free
    }

    if (g == G - 1 && tid == NTH - 1) sdtw_out[b] = result;   // cell (1023,1023)
}

// ---------------- fallback: R17-proven single-block kernel ----------------
#define FB_KS 16
#define FB_DOW 79
#define FB_SKEW (FB_DOW * 3 + 63)     // 300
#define FB_NB ((FB_SKEW + T + FB_KS - 1) / FB_KS)   // 83

__global__ __launch_bounds__(NTH) void sdtw_fb(const float* __restrict__ pred,
                                               const float* __restrict__ targ,
                                               float* __restrict__ sdtw_out) {
    __shared__ float p[T];
    __shared__ float ring[3][T];
    const int b = blockIdx.x;
    const int tid = threadIdx.x;
    const int wv = tid >> 6, ln = tid & 63;
    const int myoff = FB_DOW * wv + ln;
    ((float4*)p)[tid] = ((const float4*)(pred + b * T))[tid];
    const float4 t4 = ((const float4*)(targ + b * T))[tid];
    const float tj0 = t4.x, tj1 = t4.y, tj2 = t4.z, tj3 = t4.w;
    const float zcc = (tid == 0) ? 0.0f : BIGF;
    float top0 = BIGF, top1 = BIGF, top2 = BIGF, top3 = BIGF;
    float corner = BIGF, rc = BIGF, result = 0.0f;
    __syncthreads();
    for (int sb = 0; sb < FB_NB; ++sb) {
        const int ics = sb * FB_KS - myoff;
        float rl[FB_KS];
#pragma unroll
        for (int so = 0; so < FB_KS; ++so) rl[so] = BIGF;
        if (ln == 0 && wv > 0) {
#pragma unroll
            for (int so = 0; so < FB_KS; ++so) rl[so] = ring[wv - 1][(ics + so) & (T - 1)];
        }
        float Dv0[FB_KS], Dv1[FB_KS], Dv2[FB_KS], Dv3[FB_KS];
#pragma unroll
        for (int so = 0; so < FB_KS; ++so) {
            const float pr = p[(ics + so) & (T - 1)];
            const float d0 = pr - tj0, d1 = pr - tj1, d2 = pr - tj2, d3 = pr - tj3;
            Dv0[so] = d0 * d0; Dv1[so] = d1 * d1; Dv2[so] = d2 * d2; Dv3[so] = d3 * d3;
        }
#pragma unroll
        for (int so = 0; so < FB_KS; ++so) {
            const int ic = ics + so;
            const float lf = lane_shr1(rl[so], rc);
            const bool r0 = (ic == 0);
            const float t0 = r0 ? BIGF : top0;
            const float t1 = r0 ? BIGF : top1;
            const float t2 = r0 ? BIGF : top2;
            const float t3 = r0 ? BIGF : top3;
            const float cc = r0 ? zcc : corner;
            const float c0 = Dv0[so] + softmin3(cc, t0, lf);
            const float c1 = Dv1[so] + softmin3(t0, t1, c0);
            const float c2 = Dv2[so] + softmin3(t1, t2, c1);
            const float c3 = Dv3[so] + softmin3(t2, t3, c2);
            rc = c3; top0 = c0; top1 = c1; top2 = c2; top3 = c3;
            corner = lf;
            if ((unsigned)ic < (unsigned)T) result = c3;
            if (ln == 63 && wv < 3 && (unsigned)ic < (unsigned)T) ring[wv][ic] = c3;
        }
        __syncthreads();
    }
    if (tid == NTH - 1) sdtw_out[b] = result;
}

// Single block: QTSE reduction over all B*T elements + combine.
__global__ __launch_bounds__(1024) void finish_kernel(const float* __restrict__ pred,
                                                      const float* __restrict__ targ,
                                                      const float* __restrict__ sdtw,
                                                      float* __restrict__ out) {
    const int tid = threadIdx.x;
    float acc = 0.0f;
    for (int idx = tid; idx < BATCH * T; idx += 1024) {
        const float e = pred[idx] - targ[idx];
        acc += e * e * __expf(KQTSE_ * e);
    }
    for (int off = 32; off; off >>= 1) acc += __shfl_down(acc, off, 64);
    __shared__ float red[16];
    const int wave = tid >> 6, lane = tid & 63;
    if (lane == 0) red[wave] = acc;
    __syncthreads();
    if (tid == 0) {
        float q = 0.0f;
        for (int w = 0; w < 16; ++w) q += red[w];
        q /= (float)(BATCH * T);
        float s = 0.0f;
        for (int bb = 0; bb < BATCH; ++bb) s += sdtw[bb];
        s /= (float)BATCH;
        out[0] = 0.1f * s + 1.0f * q;
    }
}

extern "C" void kernel_launch(void* const* d_in, const int* in_sizes, int n_in,
                              void* d_out, int out_size, void* d_ws, size_t ws_size,
                              hipStream_t stream) {
    const float* pred = (const float*)d_in[0];
    const float* targ = (const float*)d_in[1];
    float* out = (float*)d_out;

    if (ws_size >= WS_NEEDED) {
        float* edges = (float*)d_ws;
        float* sdtw = (float*)((char*)d_ws + SDTW_OFF);
        hipMemsetAsync(d_ws, 0xAA, EDGE_BYTES, stream);   // sentinel-fill edge buffer
        sdtw_pipe<<<BATCH * G, NTH, 0, stream>>>(pred, targ, edges, sdtw);
        finish_kernel<<<1, 1024, 0, stream>>>(pred, targ, sdtw, out);
    } else {
        float* sdtw = (float*)d_ws;   // 32 floats
        sdtw_fb<<<BATCH, NTH, 0, stream>>>(pred, targ, sdtw);
        finish_kernel<<<1, 1024, 0, stream>>>(pred, targ, sdtw, out);
    }
}

// Round 19
// 192.189 us; speedup vs baseline: 1.2713x; 1.2713x over previous
//
#include <hip/hip_runtime.h>
#include <hip/hip_bf16.h>

#define BATCH 32
#define T 1024
#define WVS 8
#define NTH (WVS * 64)            // 512 threads, 2 cols/thread
#define KS 8                      // steps per barrier window
#define DOW 71                    // inter-wave offset (R14-proven)
#define BIGF 1e10f
#define K2f 14.426950408889634f   // 1/(gamma*ln2), gamma=0.1
#define GLN2f 0.0693147180559945f // gamma*ln2
#define KQTSE_ 0.1f

// ws layout (floats): 4 diagonal arrays [BATCH][T] + sdtw[32] + qtse[32]
#define DG (BATCH * T)
#define OFF_AF 0
#define OFF_BF DG
#define OFF_AB (2 * DG)
#define OFF_BB (3 * DG)
#define SDTW_OFFF (4 * DG)
#define WS_NEEDED ((size_t)(4 * DG + 2 * BATCH) * 4)

// Raw v_exp_f32 (R14-proven: exp2f's __ocml fixup was ~40% of cell issue).
__device__ __forceinline__ float fexp2(float x) {
    float r;
    asm("v_exp_f32 %0, %1" : "=v"(r) : "v"(x));
    return r;
}

// Exact softmin_gamma(a,b,c): m - g*ln(1 + 2^{K(m-md)} + 2^{K(m-M)}) (one exp folded).
__device__ __forceinline__ float softmin3(float a, float b, float c) {
    float m  = fminf(fminf(a, b), c);             // v_min3_f32
    float M  = fmaxf(fmaxf(a, b), c);             // v_max3_f32
    float md = __builtin_amdgcn_fmed3f(a, b, c);  // v_med3_f32
    float mk = m * K2f;
    float e1 = fexp2(fmaf(-K2f, md, mk));
    float e2 = fexp2(fmaf(-K2f, M, mk));
    return fmaf(-GLN2f, __log2f(1.0f + e1 + e2), m);
}

// lane i gets src[lane i-1]; lane 0 keeps `old` (bound_ctrl=false fuses the select).
__device__ __forceinline__ float lane_shr1(float old, float src) {
    return __int_as_float(__builtin_amdgcn_update_dpp(
        __float_as_int(old), __float_as_int(src), 0x138, 0xF, 0xF, false));
}

// Half-sweep: the R14-proven W8C2 skewed-wave systolic kernel, run only far
// enough to produce two anti-diagonals, for 64 blocks (32 fw + 32 bw).
// dir=0: forward F. dir=1: backward B~ = same recurrence on index-reversed
// pred/targ (B~(i,j) = D_ij + softmin(B~(i+1,j+1), B~(i+1,j), B~(i,j+1)),
// base B~(N,M)=D_NM == forward recurrence in primed coords i'=1025-i).
// Thread (wave w, lane l) owns cols [2*tid, 2*tid+2), row ic at step
// ic + 71*w + l. Records per thread (q = (dir?1023:1021) - 2*tid):
//   rA0 = cell(col 2t,   ic=q)    sum ic+j0 = q+2t   = 1021/1023 (diag k-1 / k'A)
//   rB0 = cell(col 2t,   ic=q+1)  sum 1022/1024      (diag k / k'B)
//   rA1 = cell(col 2t+1, ic=q-1)  sum 1021/1023
//   rB1 = cell(col 2t+1, ic=q)    sum 1022/1024
// Cells on recorded diagonals depend only on earlier diagonals => exact.
// Garbage records (negative/overrun ic at edge threads) land only in export
// slots the merge never reads (verified: merge uses dgAf[0..1021],
// dgBf[0..1022], dgAb[1..1022], dgBb[1..1023]).
__global__ __launch_bounds__(NTH) void sdtw_half(const float* __restrict__ pred,
                                                 const float* __restrict__ targ,
                                                 float* __restrict__ ws) {
    __shared__ float p[T];
    __shared__ float ring[WVS - 1][T];   // 28 KB

    const int blk = blockIdx.x;
    const int b = blk & (BATCH - 1);
    const int dir = blk >> 5;            // 0 = forward, 1 = backward
    const int tid = threadIdx.x;
    const int wv = tid >> 6;
    const int ln = tid & 63;
    const int myoff = DOW * wv + ln;

    // stage p (index-reversed for backward)
    const float2 pv2 = ((const float2*)(pred + b * T))[tid];
    if (dir == 0) {
        ((float2*)p)[tid] = pv2;
    } else {
        p[T - 1 - 2 * tid] = pv2.x;
        p[T - 2 - 2 * tid] = pv2.y;
    }
    const int c0g = dir ? (T - 1 - 2 * tid) : (2 * tid);       // orig targ idx of col j0=2tid
    const int c1g = dir ? (T - 2 - 2 * tid) : (2 * tid + 1);
    const float tj0 = targ[b * T + c0g];
    const float tj1 = targ[b * T + c1g];
    const float zcc = (tid == 0) ? 0.0f : BIGF;

    const int q = (dir ? 1023 : 1021) - 2 * tid;
    const int nb = 128 + dir;            // fw needs ic<=1022 (1024 steps); bw ic<=1024

    float top0 = BIGF, top1 = BIGF, corner = BIGF, rc = BIGF;
    float rA0 = BIGF, rB0 = BIGF, rA1 = BIGF, rB1 = BIGF;

    __syncthreads();

    for (int sb = 0; sb < nb; ++sb) {
        const int ics = sb * KS - myoff;

        float rl[KS];
#pragma unroll
        for (int so = 0; so < KS; ++so) rl[so] = BIGF;
        if (ln == 0 && wv > 0) {
#pragma unroll
            for (int so = 0; so < KS; ++so) rl[so] = ring[wv - 1][(ics + so) & (T - 1)];
        }

        float Dv0[KS], Dv1[KS];
#pragma unroll
        for (int so = 0; so < KS; ++so) {
            const float pr = p[(ics + so) & (T - 1)];
            const float d0 = pr - tj0;
            const float d1 = pr - tj1;
            Dv0[so] = d0 * d0;
            Dv1[so] = d1 * d1;
        }

#pragma unroll
        for (int so = 0; so < KS; ++so) {
            const int ic = ics + so;
            const float lf = lane_shr1(rl[so], rc);
            const bool r0 = (ic == 0);
            const float t0 = r0 ? BIGF : top0;
            const float t1 = r0 ? BIGF : top1;
            const float cc = r0 ? zcc : corner;

            const float c00 = Dv0[so] + softmin3(cc, t0, lf);
            const float c01 = Dv1[so] + softmin3(t0, t1, c00);

            if (ic == q - 1) rA1 = c01;
            if (ic == q)     { rA0 = c00; rB1 = c01; }
            if (ic == q + 1) rB0 = c00;

            rc = c01; top0 = c00; top1 = c01; corner = lf;
            if (ln == 63 && wv < WVS - 1 && (unsigned)ic < (unsigned)T)
                ring[wv][ic] = c01;
        }
        __syncthreads();
    }

    float* dgA = ws + (dir ? OFF_AB : OFF_AF) + b * T;
    float* dgB = ws + (dir ? OFF_BB : OFF_BF) + b * T;
    dgA[2 * tid] = rA0;
    dgA[2 * tid + 1] = rA1;
    dgB[2 * tid] = rB0;
    dgB[2 * tid + 1] = rB1;
}

// Merge: R(N,M) = -g*ln( S1 + S2 ) with
//  S1 = sum_{i=1..1023} e^{-(F(i,1024-i) + B~(i,1024-i) - D(i,1024-i))/g}
//     F(i,1024-i) = dgBf[1023-i]; B~(i,1024-i) = dgBb[i]
//  S2 = sum_{i=1..1022} e^{-(F(i,1023-i) + B~(i+1,1024-i))/g}   (diag jumps)
//     F(i,1023-i) = dgAf[1022-i]; B~(i+1,1024-i) = dgAb[i]
// (identity hand-verified on 2x2). Also computes the batch QTSE partial.
__global__ __launch_bounds__(1024) void merge_kernel(const float* __restrict__ pred,
                                                     const float* __restrict__ targ,
                                                     float* __restrict__ ws) {
    const int b = blockIdx.x;
    const int tid = threadIdx.x;   // = i
    const float* dgAf = ws + OFF_AF + b * T;
    const float* dgBf = ws + OFF_BF + b * T;
    const float* dgAb = ws + OFF_AB + b * T;
    const float* dgBb = ws + OFF_BB + b * T;

    float t1 = BIGF, t2 = BIGF;
    if (tid >= 1) {
        const float d = pred[b * T + tid - 1] - targ[b * T + 1023 - tid];
        t1 = dgBf[1023 - tid] + dgBb[tid] - d * d;
    }
    if (tid >= 1 && tid <= 1022) {
        t2 = dgAf[1022 - tid] + dgAb[tid];
    }
    const float e = pred[b * T + tid] - targ[b * T + tid];
    float qacc = e * e * __expf(KQTSE_ * e);

    __shared__ float red[16];
    __shared__ float redq[16];
    __shared__ float bcast;
    const int wv = tid >> 6, ln = tid & 63;

    float mn = fminf(t1, t2);
    for (int off = 32; off; off >>= 1) mn = fminf(mn, __shfl_xor(mn, off, 64));
    if (ln == 0) red[wv] = mn;
    __syncthreads();
    if (tid == 0) {
        float m = red[0];
        for (int w = 1; w < 16; ++w) m = fminf(m, red[w]);
        bcast = m;
    }
    __syncthreads();
    const float m = bcast;

    float s = fexp2((m - t1) * K2f) + fexp2((m - t2) * K2f);  // BIG defaults -> 0
    for (int off = 32; off; off >>= 1) s += __shfl_xor(s, off, 64);
    for (int off = 32; off; off >>= 1) qacc += __shfl_xor(qacc, off, 64);
    __syncthreads();
    if (ln == 0) { red[wv] = s; redq[wv] = qacc; }
    __syncthreads();
    if (tid == 0) {
        float tot = 0.0f, qt = 0.0f;
        for (int w = 0; w < 16; ++w) { tot += red[w]; qt += redq[w]; }
        ws[SDTW_OFFF + b] = fmaf(-GLN2f, __log2f(tot), m);
        ws[SDTW_OFFF + BATCH + b] = qt;
    }
}

// Combine 32 sdtw + 32 qtse partials into the scalar loss.
__global__ __launch_bounds__(64) void finish_small(const float* __restrict__ sd,
                                                   float* __restrict__ out) {
    const int l = threadIdx.x;
    float s = (l < BATCH) ? sd[l] : 0.0f;
    float qv = (l < BATCH) ? sd[BATCH + l] : 0.0f;
    for (int off = 32; off; off >>= 1) {
        s += __shfl_down(s, off, 64);
        qv += __shfl_down(qv, off, 64);
    }
    if (l == 0) out[0] = 0.1f * (s / (float)BATCH) + qv / (float)(BATCH * T);
}

// ---------------- fallback: R17-proven single-block kernel (tiny ws) ----------------
#define FB_KS 16
#define FB_DOW 79
#define FB_NB 83

__global__ __launch_bounds__(256) void sdtw_fb(const float* __restrict__ pred,
                                               const float* __restrict__ targ,
                                               float* __restrict__ sdtw_out) {
    __shared__ float p[T];
    __shared__ float ring[3][T];
    const int b = blockIdx.x;
    const int tid = threadIdx.x;
    const int wv = tid >> 6, ln = tid & 63;
    const int myoff = FB_DOW * wv + ln;
    ((float4*)p)[tid] = ((const float4*)(pred + b * T))[tid];
    const float4 t4 = ((const float4*)(targ + b * T))[tid];
    const float tj0 = t4.x, tj1 = t4.y, tj2 = t4.z, tj3 = t4.w;
    const float zcc = (tid == 0) ? 0.0f : BIGF;
    float top0 = BIGF, top1 = BIGF, top2 = BIGF, top3 = BIGF;
    float corner = BIGF, rc = BIGF, result = 0.0f;
    __syncthreads();
    for (int sb = 0; sb < FB_NB; ++sb) {
        const int ics = sb * FB_KS - myoff;
        float rl[FB_KS];
#pragma unroll
        for (int so = 0; so < FB_KS; ++so) rl[so] = BIGF;
        if (ln == 0 && wv > 0) {
#pragma unroll
            for (int so = 0; so < FB_KS; ++so) rl[so] = ring[wv - 1][(ics + so) & (T - 1)];
        }
        float Dv0[FB_KS], Dv1[FB_KS], Dv2[FB_KS], Dv3[FB_KS];
#pragma unroll
        for (int so = 0; so < FB_KS; ++so) {
            const float pr = p[(ics + so) & (T - 1)];
            const float d0 = pr - tj0, d1 = pr - tj1, d2 = pr - tj2, d3 = pr - tj3;
            Dv0[so] = d0 * d0; Dv1[so] = d1 * d1; Dv2[so] = d2 * d2; Dv3[so] = d3 * d3;
        }
#pragma unroll
        for (int so = 0; so < FB_KS; ++so) {
            const int ic = ics + so;
            const float lf = lane_shr1(rl[so], rc);
            const bool r0 = (ic == 0);
            const float t0 = r0 ? BIGF : top0;
            const float t1 = r0 ? BIGF : top1;
            const float t2 = r0 ? BIGF : top2;
            const float t3 = r0 ? BIGF : top3;
            const float cc = r0 ? zcc : corner;
            const float c0 = Dv0[so] + softmin3(cc, t0, lf);
            const float c1 = Dv1[so] + softmin3(t0, t1, c0);
            const float c2 = Dv2[so] + softmin3(t1, t2, c1);
            const float c3 = Dv3[so] + softmin3(t2, t3, c2);
            rc = c3; top0 = c0; top1 = c1; top2 = c2; top3 = c3;
            corner = lf;
            if ((unsigned)ic < (unsigned)T) result = c3;
            if (ln == 63 && wv < 3 && (unsigned)ic < (unsigned)T) ring[wv][ic] = c3;
        }
        __syncthreads();
    }
    if (tid == 255) sdtw_out[b] = result;
}

__global__ __launch_bounds__(1024) void finish_kernel(const float* __restrict__ pred,
                                                      const float* __restrict__ targ,
                                                      const float* __restrict__ sdtw,
                                                      float* __restrict__ out) {
    const int tid = threadIdx.x;
    float acc = 0.0f;
    for (int idx = tid; idx < BATCH * T; idx += 1024) {
        const float e = pred[idx] - targ[idx];
        acc += e * e * __expf(KQTSE_ * e);
    }
    for (int off = 32; off; off >>= 1) acc += __shfl_down(acc, off, 64);
    __shared__ float red[16];
    const int wave = tid >> 6, lane = tid & 63;
    if (lane == 0) red[wave] = acc;
    __syncthreads();
    if (tid == 0) {
        float qv = 0.0f;
        for (int w = 0; w < 16; ++w) qv += red[w];
        qv /= (float)(BATCH * T);
        float s = 0.0f;
        for (int bb = 0; bb < BATCH; ++bb) s += sdtw[bb];
        s /= (float)BATCH;
        out[0] = 0.1f * s + 1.0f * qv;
    }
}

extern "C" void kernel_launch(void* const* d_in, const int* in_sizes, int n_in,
                              void* d_out, int out_size, void* d_ws, size_t ws_size,
                              hipStream_t stream) {
    const float* pred = (const float*)d_in[0];
    const float* targ = (const float*)d_in[1];
    float* out = (float*)d_out;

    if (ws_size >= WS_NEEDED) {
        float* ws = (float*)d_ws;
        sdtw_half<<<BATCH * 2, NTH, 0, stream>>>(pred, targ, ws);
        merge_kernel<<<BATCH, 1024, 0, stream>>>(pred, targ, ws);
        finish_small<<<1, 64, 0, stream>>>(ws + SDTW_OFFF, out);
    } else {
        float* sdtw = (float*)d_ws;   // 32 floats
        sdtw_fb<<<BATCH, 256, 0, stream>>>(pred, targ, sdtw);
        finish_kernel<<<1, 1024, 0, stream>>>(pred, targ, sdtw, out);
    }
}

// Round 20
// 172.637 us; speedup vs baseline: 1.4153x; 1.1133x over previous
//
#include <hip/hip_runtime.h>
#include <hip/hip_bf16.h>

#define BATCH 32
#define T 1024
#define WVS 8
#define NTH (WVS * 64)            // 512 threads, 2 cols/thread
#define KS 8                      // steps per barrier window
#define DOW 71                    // inter-rank offset (63 + KS, ring proof)
#define BIGF 1e10f
#define K2f 14.426950408889634f   // 1/(gamma*ln2), gamma=0.1
#define GLN2f 0.0693147180559945f // gamma*ln2
#define KQTSE_ 0.1f

// ws layout (floats): 4 diagonal arrays [BATCH][T] + sdtw[32] + qtse[32]
#define DG (BATCH * T)
#define OFF_AF 0
#define OFF_BF DG
#define OFF_AB (2 * DG)
#define OFF_BB (3 * DG)
#define SDTW_OFFF (4 * DG)
#define WS_NEEDED ((size_t)(4 * DG + 2 * BATCH) * 4)

// Raw v_exp_f32 (R14-proven: exp2f's __ocml fixup was ~40% of cell issue).
__device__ __forceinline__ float fexp2(float x) {
    float r;
    asm("v_exp_f32 %0, %1" : "=v"(r) : "v"(x));
    return r;
}

// Exact softmin_gamma(a,b,c): m - g*ln(1 + 2^{K(m-md)} + 2^{K(m-M)}) (one exp folded).
__device__ __forceinline__ float softmin3(float a, float b, float c) {
    float m  = fminf(fminf(a, b), c);             // v_min3_f32
    float M  = fmaxf(fmaxf(a, b), c);             // v_max3_f32
    float md = __builtin_amdgcn_fmed3f(a, b, c);  // v_med3_f32
    float mk = m * K2f;
    float e1 = fexp2(fmaf(-K2f, md, mk));
    float e2 = fexp2(fmaf(-K2f, M, mk));
    return fmaf(-GLN2f, __log2f(1.0f + e1 + e2), m);
}

// lane i gets src[lane i-1]; lane 0 keeps `old` (bound_ctrl=false fuses the select).
__device__ __forceinline__ float lane_shr1(float old, float src) {
    return __int_as_float(__builtin_amdgcn_update_dpp(
        __float_as_int(old), __float_as_int(src), 0x138, 0xF, 0xF, false));
}

// Half-sweep (R19-proven recording/merge scheme) + R20 additions:
//  1) RANK PERMUTATION: wave w gets column-strip rank = (w<4 ? 2w : 15-2w).
//     SIMD s hosts waves s, s+4 -> rank pairs (0,7),(2,5),(4,3),(6,1) whose
//     active-window counts (129,16),(96,48),(64,80),(32,112) all sum ~144:
//     balanced per-SIMD issue. All skew/ring logic runs in RANK space
//     (myoff = 71*rank + ln), so the R14/R19 ordering proofs carry verbatim.
//  2) WINDOW GATING: rank r only needs steps [71r, 1022+2*dir-57r] (lane-0
//     row 0 through the last record step). Outside [wA,wB] the wave skips the
//     whole window body (wave-uniform scalar branch -> ~zero issue) and only
//     joins the barrier. 44% of all wave-windows are gated off. Gated waves'
//     state stays BIGF (the correct boundary value); ring writers provably
//     remain active through every row their reader needs (writer covers rows
//     <= 1024+2d-128r vs reader need 1022+2d-128r).
// Records (q = (dir?1023:1021) - 2*vtid), exports, and the merge identity are
// byte-identical to the R19-passing kernel.
__global__ __launch_bounds__(NTH) void sdtw_half(const float* __restrict__ pred,
                                                 const float* __restrict__ targ,
                                                 float* __restrict__ ws) {
    __shared__ float p[T];
    __shared__ float ring[WVS - 1][T];   // 28 KB, indexed by rank

    const int blk = blockIdx.x;
    const int b = blk & (BATCH - 1);
    const int dir = blk >> 5;            // 0 = forward, 1 = backward
    const int tid = threadIdx.x;
    const int wv = tid >> 6;
    const int ln = tid & 63;
    const int rank = (wv < 4) ? (2 * wv) : (15 - 2 * wv);   // SIMD-balancing perm
    const int vtid = (rank << 6) + ln;   // systolic position (column owner)
    const int myoff = DOW * rank + ln;

    // stage p (index-reversed for backward) — any bijection over tid is fine
    const float2 pv2 = ((const float2*)(pred + b * T))[tid];
    if (dir == 0) {
        ((float2*)p)[tid] = pv2;
    } else {
        p[T - 1 - 2 * tid] = pv2.x;
        p[T - 2 - 2 * tid] = pv2.y;
    }
    const int c0g = dir ? (T - 1 - 2 * vtid) : (2 * vtid);   // orig targ idx of col j0
    const int c1g = dir ? (T - 2 - 2 * vtid) : (2 * vtid + 1);
    const float tj0 = targ[b * T + c0g];
    const float tj1 = targ[b * T + c1g];
    const float zcc = (vtid == 0) ? 0.0f : BIGF;

    const int q = (dir ? 1023 : 1021) - 2 * vtid;
    const int nb = 128 + dir;
    const int wA = (DOW * rank) >> 3;                        // first useful window
    const int wB = (1022 + 2 * dir - 57 * rank) >> 3;        // last record window

    float top0 = BIGF, top1 = BIGF, corner = BIGF, rc = BIGF;
    float rA0 = BIGF, rB0 = BIGF, rA1 = BIGF, rB1 = BIGF;

    __syncthreads();

    for (int sb = 0; sb < nb; ++sb) {
        if (sb >= wA && sb <= wB) {      // wave-uniform gate: skip dead windows
            const int ics = sb * KS - myoff;

            float rl[KS];
#pragma unroll
            for (int so = 0; so < KS; ++so) rl[so] = BIGF;
            if (ln == 0 && rank > 0) {
#pragma unroll
                for (int so = 0; so < KS; ++so) rl[so] = ring[rank - 1][(ics + so) & (T - 1)];
            }

            float Dv0[KS], Dv1[KS];
#pragma unroll
            for (int so = 0; so < KS; ++so) {
                const float pr = p[(ics + so) & (T - 1)];
                const float d0 = pr - tj0;
                const float d1 = pr - tj1;
                Dv0[so] = d0 * d0;
                Dv1[so] = d1 * d1;
            }

#pragma unroll
            for (int so = 0; so < KS; ++so) {
                const int ic = ics + so;
                const float lf = lane_shr1(rl[so], rc);
                const bool r0 = (ic == 0);
                const float t0 = r0 ? BIGF : top0;
                const float t1 = r0 ? BIGF : top1;
                const float cc = r0 ? zcc : corner;

                const float c00 = Dv0[so] + softmin3(cc, t0, lf);
                const float c01 = Dv1[so] + softmin3(t0, t1, c00);

                if (ic == q - 1) rA1 = c01;
                if (ic == q)     { rA0 = c00; rB1 = c01; }
                if (ic == q + 1) rB0 = c00;

                rc = c01; top0 = c00; top1 = c01; corner = lf;
                if (ln == 63 && rank < WVS - 1 && (unsigned)ic < (unsigned)T)
                    ring[rank][ic] = c01;
            }
        }
        __syncthreads();
    }

    float* dgA = ws + (dir ? OFF_AB : OFF_AF) + b * T;
    float* dgB = ws + (dir ? OFF_BB : OFF_BF) + b * T;
    dgA[2 * vtid] = rA0;
    dgA[2 * vtid + 1] = rA1;
    dgB[2 * vtid] = rB0;
    dgB[2 * vtid + 1] = rB1;
}

// Merge: R(N,M) = -g*ln( S1 + S2 ) with
//  S1 = sum_{i=1..1023} e^{-(F(i,1024-i) + B~(i,1024-i) - D(i,1024-i))/g}
//  S2 = sum_{i=1..1022} e^{-(F(i,1023-i) + B~(i+1,1024-i))/g}
// (identity hand-verified on 2x2; R19-passing). Also computes batch QTSE.
__global__ __launch_bounds__(1024) void merge_kernel(const float* __restrict__ pred,
                                                     const float* __restrict__ targ,
                                                     float* __restrict__ ws) {
    const int b = blockIdx.x;
    const int tid = threadIdx.x;   // = i
    const float* dgAf = ws + OFF_AF + b * T;
    const float* dgBf = ws + OFF_BF + b * T;
    const float* dgAb = ws + OFF_AB + b * T;
    const float* dgBb = ws + OFF_BB + b * T;

    float t1 = BIGF, t2 = BIGF;
    if (tid >= 1) {
        const float d = pred[b * T + tid - 1] - targ[b * T + 1023 - tid];
        t1 = dgBf[1023 - tid] + dgBb[tid] - d * d;
    }
    if (tid >= 1 && tid <= 1022) {
        t2 = dgAf[1022 - tid] + dgAb[tid];
    }
    const float e = pred[b * T + tid] - targ[b * T + tid];
    float qacc = e * e * __expf(KQTSE_ * e);

    __shared__ float red[16];
    __shared__ float redq[16];
    __shared__ float bcast;
    const int wv = tid >> 6, ln = tid & 63;

    float mn = fminf(t1, t2);
    for (int off = 32; off; off >>= 1) mn = fminf(mn, __shfl_xor(mn, off, 64));
    if (ln == 0) red[wv] = mn;
    __syncthreads();
    if (tid == 0) {
        float m = red[0];
        for (int w = 1; w < 16; ++w) m = fminf(m, red[w]);
        bcast = m;
    }
    __syncthreads();
    const float m = bcast;

    float s = fexp2((m - t1) * K2f) + fexp2((m - t2) * K2f);  // BIG defaults -> 0
    for (int off = 32; off; off >>= 1) s += __shfl_xor(s, off, 64);
    for (int off = 32; off; off >>= 1) qacc += __shfl_xor(qacc, off, 64);
    __syncthreads();
    if (ln == 0) { red[wv] = s; redq[wv] = qacc; }
    __syncthreads();
    if (tid == 0) {
        float tot = 0.0f, qt = 0.0f;
        for (int w = 0; w < 16; ++w) { tot += red[w]; qt += redq[w]; }
        ws[SDTW_OFFF + b] = fmaf(-GLN2f, __log2f(tot), m);
        ws[SDTW_OFFF + BATCH + b] = qt;
    }
}

// Combine 32 sdtw + 32 qtse partials into the scalar loss.
__global__ __launch_bounds__(64) void finish_small(const float* __restrict__ sd,
                                                   float* __restrict__ out) {
    const int l = threadIdx.x;
    float s = (l < BATCH) ? sd[l] : 0.0f;
    float qv = (l < BATCH) ? sd[BATCH + l] : 0.0f;
    for (int off = 32; off; off >>= 1) {
        s += __shfl_down(s, off, 64);
        qv += __shfl_down(qv, off, 64);
    }
    if (l == 0) out[0] = 0.1f * (s / (float)BATCH) + qv / (float)(BATCH * T);
}

// ---------------- fallback: R17-proven single-block kernel (tiny ws) ----------------
#define FB_KS 16
#define FB_DOW 79
#define FB_NB 83

__global__ __launch_bounds__(256) void sdtw_fb(const float* __restrict__ pred,
                                               const float* __restrict__ targ,
                                               float* __restrict__ sdtw_out) {
    __shared__ float p[T];
    __shared__ float ring[3][T];
    const int b = blockIdx.x;
    const int tid = threadIdx.x;
    const int wv = tid >> 6, ln = tid & 63;
    const int myoff = FB_DOW * wv + ln;
    ((float4*)p)[tid] = ((const float4*)(pred + b * T))[tid];
    const float4 t4 = ((const float4*)(targ + b * T))[tid];
    const float tj0 = t4.x, tj1 = t4.y, tj2 = t4.z, tj3 = t4.w;
    const float zcc = (tid == 0) ? 0.0f : BIGF;
    float top0 = BIGF, top1 = BIGF, top2 = BIGF, top3 = BIGF;
    float corner = BIGF, rc = BIGF, result = 0.0f;
    __syncthreads();
    for (int sb = 0; sb < FB_NB; ++sb) {
        const int ics = sb * FB_KS - myoff;
        float rl[FB_KS];
#pragma unroll
        for (int so = 0; so < FB_KS; ++so) rl[so] = BIGF;
        if (ln == 0 && wv > 0) {
#pragma unroll
            for (int so = 0; so < FB_KS; ++so) rl[so] = ring[wv - 1][(ics + so) & (T - 1)];
        }
        float Dv0[FB_KS], Dv1[FB_KS], Dv2[FB_KS], Dv3[FB_KS];
#pragma unroll
        for (int so = 0; so < FB_KS; ++so) {
            const float pr = p[(ics + so) & (T - 1)];
            const float d0 = pr - tj0, d1 = pr - tj1, d2 = pr - tj2, d3 = pr - tj3;
            Dv0[so] = d0 * d0; Dv1[so] = d1 * d1; Dv2[so] = d2 * d2; Dv3[so] = d3 * d3;
        }
#pragma unroll
        for (int so = 0; so < FB_KS; ++so) {
            const int ic = ics + so;
            const float lf = lane_shr1(rl[so], rc);
            const bool r0 = (ic == 0);
            const float t0 = r0 ? BIGF : top0;
            const float t1 = r0 ? BIGF : top1;
            const float t2 = r0 ? BIGF : top2;
            const float t3 = r0 ? BIGF : top3;
            const float cc = r0 ? zcc : corner;
            const float c0 = Dv0[so] + softmin3(cc, t0, lf);
            const float c1 = Dv1[so] + softmin3(t0, t1, c0);
            const float c2 = Dv2[so] + softmin3(t1, t2, c1);
            const float c3 = Dv3[so] + softmin3(t2, t3, c2);
            rc = c3; top0 = c0; top1 = c1; top2 = c2; top3 = c3;
            corner = lf;
            if ((unsigned)ic < (unsigned)T) result = c3;
            if (ln == 63 && wv < 3 && (unsigned)ic < (unsigned)T) ring[wv][ic] = c3;
        }
        __syncthreads();
    }
    if (tid == 255) sdtw_out[b] = result;
}

__global__ __launch_bounds__(1024) void finish_kernel(const float* __restrict__ pred,
                                                      const float* __restrict__ targ,
                                                      const float* __restrict__ sdtw,
                                                      float* __restrict__ out) {
    const int tid = threadIdx.x;
    float acc = 0.0f;
    for (int idx = tid; idx < BATCH * T; idx += 1024) {
        const float e = pred[idx] - targ[idx];
        acc += e * e * __expf(KQTSE_ * e);
    }
    for (int off = 32; off; off >>= 1) acc += __shfl_down(acc, off, 64);
    __shared__ float red[16];
    const int wave = tid >> 6, lane = tid & 63;
    if (lane == 0) red[wave] = acc;
    __syncthreads();
    if (tid == 0) {
        float qv = 0.0f;
        for (int w = 0; w < 16; ++w) qv += red[w];
        qv /= (float)(BATCH * T);
        float s = 0.0f;
        for (int bb = 0; bb < BATCH; ++bb) s += sdtw[bb];
        s /= (float)BATCH;
        out[0] = 0.1f * s + 1.0f * qv;
    }
}

extern "C" void kernel_launch(void* const* d_in, const int* in_sizes, int n_in,
                              void* d_out, int out_size, void* d_ws, size_t ws_size,
                              hipStream_t stream) {
    const float* pred = (const float*)d_in[0];
    const float* targ = (const float*)d_in[1];
    float* out = (float*)d_out;

    if (ws_size >= WS_NEEDED) {
        float* ws = (float*)d_ws;
        sdtw_half<<<BATCH * 2, NTH, 0, stream>>>(pred, targ, ws);
        merge_kernel<<<BATCH, 1024, 0, stream>>>(pred, targ, ws);
        finish_small<<<1, 64, 0, stream>>>(ws + SDTW_OFFF, out);
    } else {
        float* sdtw = (float*)d_ws;   // 32 floats
        sdtw_fb<<<BATCH, 256, 0, stream>>>(pred, targ, sdtw);
        finish_kernel<<<1, 1024, 0, stream>>>(pred, targ, sdtw, out);
    }
}

// Round 21
// 171.701 us; speedup vs baseline: 1.4230x; 1.0055x over previous
//
#include <hip/hip_runtime.h>
#include <hip/hip_bf16.h>

#define BATCH 32
#define T 1024
#define WVS 8
#define NTH 512
#define KS 8
#define DOW 71                    // inter-rank offset (63 + KS, ring proof)
#define BIGF 1e10f
#define K2f 14.426950408889634f   // 1/(gamma*ln2), gamma=0.1
#define GLN2f 0.0693147180559945f // gamma*ln2
#define KQTSE_ 0.1f

// ws layout (floats): 4 diagonal arrays [BATCH][T] + sdtw[32] + qtse[32] + edges
#define DG (BATCH * T)
#define OFF_AF 0
#define OFF_BF DG
#define OFF_AB (2 * DG)
#define OFF_BB (3 * DG)
#define SDTW_OFFF (4 * DG)
#define EDGE_OFF (4 * DG + 2 * BATCH)
#define EDGE_FLTS 544             // per interface (65 chunks max + pad)
#define WS1 ((size_t)(4 * DG + 2 * BATCH) * 4)
#define WS2 ((size_t)(EDGE_OFF + 64 * EDGE_FLTS) * 4)
#define SENT_U 0xAAAAAAAAu

typedef float f32x4 __attribute__((ext_vector_type(4)));

__device__ __forceinline__ float fexp2(float x) {
    float r;
    asm("v_exp_f32 %0, %1" : "=v"(r) : "v"(x));
    return r;
}

__device__ __forceinline__ float softmin3(float a, float b, float c) {
    float m  = fminf(fminf(a, b), c);
    float M  = fmaxf(fmaxf(a, b), c);
    float md = __builtin_amdgcn_fmed3f(a, b, c);
    float mk = m * K2f;
    float e1 = fexp2(fmaf(-K2f, md, mk));
    float e2 = fexp2(fmaf(-K2f, M, mk));
    return fmaf(-GLN2f, __log2f(1.0f + e1 + e2), m);
}

__device__ __forceinline__ float lane_shr1(float old, float src) {
    return __int_as_float(__builtin_amdgcn_update_dpp(
        __float_as_int(old), __float_as_int(src), 0x138, 0xF, 0xF, false));
}

// ---- sentinel transport (R13/R15/R18-proven), 8-float chunks ----
__device__ __forceinline__ void issue_load8(const float* base, f32x4& a, f32x4& b) {
    asm volatile("global_load_dwordx4 %0, %2, off sc0 sc1\n\t"
                 "global_load_dwordx4 %1, %2, off offset:16 sc0 sc1"
                 : "=&v"(a), "=&v"(b) : "v"(base));
}
__device__ __forceinline__ void await_load8(f32x4& a, f32x4& b) {
    asm volatile("s_waitcnt vmcnt(0)" : "+v"(a), "+v"(b) :: "memory");
    __builtin_amdgcn_sched_barrier(0);
}
__device__ __forceinline__ bool has_sent(const f32x4& a, const f32x4& b) {
    return (__float_as_uint(a.x) == SENT_U) | (__float_as_uint(a.y) == SENT_U) |
           (__float_as_uint(a.z) == SENT_U) | (__float_as_uint(a.w) == SENT_U) |
           (__float_as_uint(b.x) == SENT_U) | (__float_as_uint(b.y) == SENT_U) |
           (__float_as_uint(b.z) == SENT_U) | (__float_as_uint(b.w) == SENT_U);
}
__device__ __forceinline__ void spin_load8(const float* base, f32x4& a, f32x4& b) {
    issue_load8(base, a, b);
    await_load8(a, b);
    while (has_sent(a, b)) {
        __builtin_amdgcn_s_sleep(8);
        issue_load8(base, a, b);
        await_load8(a, b);
    }
}
__device__ __forceinline__ void store_edge8(float* base, const f32x4& a, const f32x4& b) {
    asm volatile("global_store_dwordx4 %0, %1, off sc0 sc1\n\t"
                 "global_store_dwordx4 %0, %2, off offset:16 sc0 sc1"
                 :: "v"(base), "v"(a), "v"(b) : "memory");
}

// Column-panel pipelined half-sweep: 128 blocks = 32 batch x 2 dir x 2 panel.
// Panel pg owns logical cols [pg*512, pg*512+512), 1 col/thread, 8 waves with
// the R20 rank permutation + window gating. Panel 0's col-511 edge streams to
// panel 1's rank-0 lane-0 via sentinel chunks. Records (rA at ic==q, rB at
// ic==q+1, q=(dir?1023:1021)-j) and exports dgA[j]=cell(q,j), dgB[j]=cell(q+1,j)
// match the R19-verified merge identity. Gating bounds per rank are
// lane-uniform: wA=myoff>>3, wB=(1022+2dir-512pg+7r)>>3. Garbage cells
// (wrapped p reads before ic=0, rows past q+1) provably never reach a read
// slot (records exact-match ic; ring writes guarded; unread export slots:
// fw dgA[1022,1023], dgB[1023]; bw dgA[0],dgB[0] — merge never reads them).
__global__ __launch_bounds__(NTH) void sdtw_panel(const float* __restrict__ pred,
                                                  const float* __restrict__ targ,
                                                  float* __restrict__ ws) {
    __shared__ float p[T];
    __shared__ float ring[WVS - 1][T];

    const int blk = blockIdx.x;
    const int b = blk & (BATCH - 1);
    const int dir = (blk >> 5) & 1;
    const int pg = blk >> 6;
    const int tid = threadIdx.x;
    const int wv = tid >> 6;
    const int ln = tid & 63;
    const int rank = (wv < 4) ? (2 * wv) : (15 - 2 * wv);
    const int vtid = (rank << 6) + ln;      // panel-local col
    const int j = pg * 512 + vtid;          // logical col
    const int myoff = DOW * rank + ln;

    const float2 pv2 = ((const float2*)(pred + b * T))[tid];
    if (dir == 0) {
        ((float2*)p)[tid] = pv2;
    } else {
        p[T - 1 - 2 * tid] = pv2.x;
        p[T - 2 - 2 * tid] = pv2.y;
    }
    const float tj = targ[b * T + (dir ? (T - 1 - j) : j)];
    const float zcc = (j == 0) ? 0.0f : BIGF;

    const int q = (dir ? 1023 : 1021) - j;
    const int qp1 = q + 1;
    const int wA = myoff >> 3;
    const int wB = (1022 + 2 * dir - pg * 512 + 7 * rank) >> 3;
    const int nbl = ((1022 + 2 * dir - pg * 512 + 49) >> 3) + 1;   // windows this block
    const int nch = ((510 + 2 * dir) >> 3) + 1;                    // chunks per interface

    float* eb = ws + EDGE_OFF + (b + BATCH * dir) * EDGE_FLTS;
    const bool consumer = (pg == 1) && (tid == 0);                 // rank0 ln0, col 512
    const bool producing = (pg == 0) && (rank == 7) && (ln == 63); // col 511

    float top = BIGF, corner = BIGF, rc = BIGF;
    float rA = BIGF, rB = BIGF;
    float rlg[KS];
#pragma unroll
    for (int i = 0; i < KS; ++i) rlg[i] = BIGF;

    __syncthreads();

    if (consumer) {
        f32x4 a, b4;
        spin_load8(eb + 3 * KS, a, b4);   // startup cushion (chunk 3)
        spin_load8(eb, a, b4);            // chunk 0
        rlg[0] = a.x; rlg[1] = a.y; rlg[2] = a.z; rlg[3] = a.w;
        rlg[4] = b4.x; rlg[5] = b4.y; rlg[6] = b4.z; rlg[7] = b4.w;
    }

    for (int sb = 0; sb < nbl; ++sb) {
        if (sb >= wA && sb <= wB) {
            const int ics = sb * KS - myoff;

            float rl[KS];
#pragma unroll
            for (int so = 0; so < KS; ++so) rl[so] = BIGF;
            if (ln == 0) {
                if (rank > 0) {
#pragma unroll
                    for (int so = 0; so < KS; ++so) rl[so] = ring[rank - 1][(ics + so) & (T - 1)];
                } else if (pg == 1) {
#pragma unroll
                    for (int so = 0; so < KS; ++so) rl[so] = rlg[so];
                }
            }

            float Dv[KS];
#pragma unroll
            for (int so = 0; so < KS; ++so) {
                const float d = p[(ics + so) & (T - 1)] - tj;
                Dv[so] = d * d;
            }

            f32x4 na, nb4;
            const bool want = consumer && (sb + 1) < nch;
            const float* basep = eb + (sb + 1) * KS;
            if (want) issue_load8(basep, na, nb4);

            float erow[KS];
#pragma unroll
            for (int so = 0; so < KS; ++so) {
                const int ic = ics + so;
                const float lf = lane_shr1(rl[so], rc);
                const bool r0 = (ic == 0);
                const float t0 = r0 ? BIGF : top;
                const float cc = r0 ? zcc : corner;

                const float c00 = Dv[so] + softmin3(cc, t0, lf);

                if (ic == q)   rA = c00;
                if (ic == qp1) rB = c00;

                rc = c00; top = c00; corner = lf;
                erow[so] = (ic <= qp1) ? c00 : 0.0f;   // zero-pad partial final chunk
                if (ln == 63 && rank < WVS - 1 && (unsigned)ic < (unsigned)T)
                    ring[rank][ic] = c00;
            }

            if (producing && ics >= 0) {
                f32x4 ea = {erow[0], erow[1], erow[2], erow[3]};
                f32x4 eb2 = {erow[4], erow[5], erow[6], erow[7]};
                store_edge8(eb + ics, ea, eb2);
            }

            if (want) {
                await_load8(na, nb4);
                while (has_sent(na, nb4)) {
                    __builtin_amdgcn_s_sleep(2);
                    issue_load8(basep, na, nb4);
                    await_load8(na, nb4);
                }
                rlg[0] = na.x; rlg[1] = na.y; rlg[2] = na.z; rlg[3] = na.w;
                rlg[4] = nb4.x; rlg[5] = nb4.y; rlg[6] = nb4.z; rlg[7] = nb4.w;
            }
        }
        __syncthreads();
    }

    float* dgA = ws + (dir ? OFF_AB : OFF_AF) + b * T;
    float* dgB = ws + (dir ? OFF_BB : OFF_BF) + b * T;
    dgA[j] = rA;
    dgB[j] = rB;
}

// ---------------- R20-proven gated half-sweep (fallback when ws < WS2) ----------------
__global__ __launch_bounds__(NTH) void sdtw_half_g(const float* __restrict__ pred,
                                                   const float* __restrict__ targ,
                                                   float* __restrict__ ws) {
    __shared__ float p[T];
    __shared__ float ring[WVS - 1][T];
    const int blk = blockIdx.x;
    const int b = blk & (BATCH - 1);
    const int dir = blk >> 5;
    const int tid = threadIdx.x;
    const int wv = tid >> 6;
    const int ln = tid & 63;
    const int rank = (wv < 4) ? (2 * wv) : (15 - 2 * wv);
    const int vtid = (rank << 6) + ln;
    const int myoff = DOW * rank + ln;
    const float2 pv2 = ((const float2*)(pred + b * T))[tid];
    if (dir == 0) {
        ((float2*)p)[tid] = pv2;
    } else {
        p[T - 1 - 2 * tid] = pv2.x;
        p[T - 2 - 2 * tid] = pv2.y;
    }
    const int c0g = dir ? (T - 1 - 2 * vtid) : (2 * vtid);
    const int c1g = dir ? (T - 2 - 2 * vtid) : (2 * vtid + 1);
    const float tj0 = targ[b * T + c0g];
    const float tj1 = targ[b * T + c1g];
    const float zcc = (vtid == 0) ? 0.0f : BIGF;
    const int q = (dir ? 1023 : 1021) - 2 * vtid;
    const int nb = 128 + dir;
    const int wA = (DOW * rank) >> 3;
    const int wB = (1022 + 2 * dir - 57 * rank) >> 3;
    float top0 = BIGF, top1 = BIGF, corner = BIGF, rc = BIGF;
    float rA0 = BIGF, rB0 = BIGF, rA1 = BIGF, rB1 = BIGF;
    __syncthreads();
    for (int sb = 0; sb < nb; ++sb) {
        if (sb >= wA && sb <= wB) {
            const int ics = sb * KS - myoff;
            float rl[KS];
#pragma unroll
            for (int so = 0; so < KS; ++so) rl[so] = BIGF;
            if (ln == 0 && rank > 0) {
#pragma unroll
                for (int so = 0; so < KS; ++so) rl[so] = ring[rank - 1][(ics + so) & (T - 1)];
            }
            float Dv0[KS], Dv1[KS];
#pragma unroll
            for (int so = 0; so < KS; ++so) {
                const float pr = p[(ics + so) & (T - 1)];
                const float d0 = pr - tj0;
                const float d1 = pr - tj1;
                Dv0[so] = d0 * d0;
                Dv1[so] = d1 * d1;
            }
#pragma unroll
            for (int so = 0; so < KS; ++so) {
                const int ic = ics + so;
                const float lf = lane_shr1(rl[so], rc);
                const bool r0 = (ic == 0);
                const float t0 = r0 ? BIGF : top0;
                const float t1 = r0 ? BIGF : top1;
                const float cc = r0 ? zcc : corner;
                const float c00 = Dv0[so] + softmin3(cc, t0, lf);
                const float c01 = Dv1[so] + softmin3(t0, t1, c00);
                if (ic == q - 1) rA1 = c01;
                if (ic == q)     { rA0 = c00; rB1 = c01; }
                if (ic == q + 1) rB0 = c00;
                rc = c01; top0 = c00; top1 = c01; corner = lf;
                if (ln == 63 && rank < WVS - 1 && (unsigned)ic < (unsigned)T)
                    ring[rank][ic] = c01;
            }
        }
        __syncthreads();
    }
    float* dgA = ws + (dir ? OFF_AB : OFF_AF) + b * T;
    float* dgB = ws + (dir ? OFF_BB : OFF_BF) + b * T;
    dgA[2 * vtid] = rA0;
    dgA[2 * vtid + 1] = rA1;
    dgB[2 * vtid] = rB0;
    dgB[2 * vtid + 1] = rB1;
}

// Merge (R19/R20-passing identity) + batch QTSE partial.
__global__ __launch_bounds__(1024) void merge_kernel(const float* __restrict__ pred,
                                                     const float* __restrict__ targ,
                                                     float* __restrict__ ws) {
    const int b = blockIdx.x;
    const int tid = threadIdx.x;
    const float* dgAf = ws + OFF_AF + b * T;
    const float* dgBf = ws + OFF_BF + b * T;
    const float* dgAb = ws + OFF_AB + b * T;
    const float* dgBb = ws + OFF_BB + b * T;

    float t1 = BIGF, t2 = BIGF;
    if (tid >= 1) {
        const float d = pred[b * T + tid - 1] - targ[b * T + 1023 - tid];
        t1 = dgBf[1023 - tid] + dgBb[tid] - d * d;
    }
    if (tid >= 1 && tid <= 1022) {
        t2 = dgAf[1022 - tid] + dgAb[tid];
    }
    const float e = pred[b * T + tid] - targ[b * T + tid];
    float qacc = e * e * __expf(KQTSE_ * e);

    __shared__ float red[16];
    __shared__ float redq[16];
    __shared__ float bcast;
    const int wv = tid >> 6, ln = tid & 63;

    float mn = fminf(t1, t2);
    for (int off = 32; off; off >>= 1) mn = fminf(mn, __shfl_xor(mn, off, 64));
    if (ln == 0) red[wv] = mn;
    __syncthreads();
    if (tid == 0) {
        float m = red[0];
        for (int w = 1; w < 16; ++w) m = fminf(m, red[w]);
        bcast = m;
    }
    __syncthreads();
    const float m = bcast;

    float s = fexp2((m - t1) * K2f) + fexp2((m - t2) * K2f);
    for (int off = 32; off; off >>= 1) s += __shfl_xor(s, off, 64);
    for (int off = 32; off; off >>= 1) qacc += __shfl_xor(qacc, off, 64);
    __syncthreads();
    if (ln == 0) { red[wv] = s; redq[wv] = qacc; }
    __syncthreads();
    if (tid == 0) {
        float tot = 0.0f, qt = 0.0f;
        for (int w = 0; w < 16; ++w) { tot += red[w]; qt += redq[w]; }
        ws[SDTW_OFFF + b] = fmaf(-GLN2f, __log2f(tot), m);
        ws[SDTW_OFFF + BATCH + b] = qt;
    }
}

__global__ __launch_bounds__(64) void finish_small(const float* __restrict__ sd,
                                                   float* __restrict__ out) {
    const int l = threadIdx.x;
    float s = (l < BATCH) ? sd[l] : 0.0f;
    float qv = (l < BATCH) ? sd[BATCH + l] : 0.0f;
    for (int off = 32; off; off >>= 1) {
        s += __shfl_down(s, off, 64);
        qv += __shfl_down(qv, off, 64);
    }
    if (l == 0) out[0] = 0.1f * (s / (float)BATCH) + qv / (float)(BATCH * T);
}

extern "C" void kernel_launch(void* const* d_in, const int* in_sizes, int n_in,
                              void* d_out, int out_size, void* d_ws, size_t ws_size,
                              hipStream_t stream) {
    const float* pred = (const float*)d_in[0];
    const float* targ = (const float*)d_in[1];
    float* out = (float*)d_out;
    float* ws = (float*)d_ws;

    if (ws_size >= WS2) {
        hipMemsetAsync((char*)d_ws + EDGE_OFF * 4, 0xAA, 64 * EDGE_FLTS * 4, stream);
        sdtw_panel<<<BATCH * 4, NTH, 0, stream>>>(pred, targ, ws);
    } else {
        sdtw_half_g<<<BATCH * 2, NTH, 0, stream>>>(pred, targ, ws);
    }
    merge_kernel<<<BATCH, 1024, 0, stream>>>(pred, targ, ws);
    finish_small<<<1, 64, 0, stream>>>(ws + SDTW_OFFF, out);
}